// Round 7
// baseline (224.715 us; speedup 1.0000x reference)
//
#include <hip/hip_runtime.h>

// InfoNCE/contrastive MVN loss:
// loss = mean_i( LSE_j((p_i.g_j - 0.5|g_j|^2)/nv) - (p_i.g_i - 0.5|g_i|^2)/nv ) * 2nv
// B = 8192, D = 256, fp32 inputs, scalar fp32 output.
// Main kernel: bf16 MFMA GEMM (P pre-scaled by s=log2e/nv) fused with online
// base-2 LSE. 32-row G tiles double-buffered via global_load_lds (33KB LDS),
// grid 1024 -> 4 blocks/CU, 8 waves/SIMD. Dual-base imm-offset ds_reads,
// acc init from LDS, raw v_exp_f32, setprio around MFMA cluster.

typedef short short8 __attribute__((ext_vector_type(8)));
typedef float f32x4 __attribute__((ext_vector_type(4)));

#define LN2F 0.6931471805599453f
#define LOG2EF 1.4426950408889634f
#define NB 8192
#define ND 256
#define NCHUNK 32   // column chunks; chunk = 256 cols = 8 tiles of 32

#define AS1 __attribute__((address_space(1)))
#define AS3 __attribute__((address_space(3)))

__device__ __forceinline__ unsigned short f2bf(float f) {
  unsigned u = __float_as_uint(f);
  u += 0x7FFFu + ((u >> 16) & 1u);   // round-to-nearest-even
  return (unsigned short)(u >> 16);
}

__device__ __forceinline__ float fexp2(float x) {
#if __has_builtin(__builtin_amdgcn_exp2f)
  return __builtin_amdgcn_exp2f(x);   // raw v_exp_f32
#else
  float r;
  asm("v_exp_f32 %0, %1\n\ts_nop 1" : "=v"(r) : "v"(x));
  return r;
#endif
}

// ---- kernel 1: convert to bf16 (P pre-scaled) + exact fp32 row stats -----
__global__ __launch_bounds__(256) void vmse_prep(
    const float* __restrict__ pred, const float* __restrict__ gt,
    const float* __restrict__ sigma,
    unsigned short* __restrict__ Ah, unsigned short* __restrict__ Bh,
    float* __restrict__ diag, float* __restrict__ gnorm,
    float* __restrict__ ghs)
{
  const float nv = sigma[0] * sigma[0];
  const float s = LOG2EF / nv;
  const int row = blockIdx.x * 4 + (threadIdx.x >> 6);
  const int lane = threadIdx.x & 63;
  const float4 p = *(const float4*)(pred + row * ND + lane * 4);
  const float4 g = *(const float4*)(gt   + row * ND + lane * 4);
  ushort4 pa, ga;
  pa.x = f2bf(p.x * s); pa.y = f2bf(p.y * s);
  pa.z = f2bf(p.z * s); pa.w = f2bf(p.w * s);
  ga.x = f2bf(g.x); ga.y = f2bf(g.y); ga.z = f2bf(g.z); ga.w = f2bf(g.w);
  *(ushort4*)(Ah + row * ND + lane * 4) = pa;
  *(ushort4*)(Bh + row * ND + lane * 4) = ga;
  float dd = p.x * g.x + p.y * g.y + p.z * g.z + p.w * g.w;
  float gg = g.x * g.x + g.y * g.y + g.z * g.z + g.w * g.w;
  #pragma unroll
  for (int off = 1; off < 64; off <<= 1) {
    dd += __shfl_xor(dd, off);
    gg += __shfl_xor(gg, off);
  }
  if (lane == 0) {
    diag[row] = dd;
    gnorm[row] = gg;
    ghs[row] = -0.5f * s * gg;   // NEGATED base-2 logit offset (acc init)
  }
}

// per-4-logit online LSE epilogue
__device__ __forceinline__ void epi(const f32x4 z, float& m, float& l) {
  const float tmax = fmaxf(fmaxf(z[0], z[1]), fmaxf(z[2], z[3]));
  if (__any(tmax > m + 8.0f)) {      // T13 defer-max, rarely taken
    const float nm = fmaxf(m, tmax);
    l *= fexp2(m - nm);
    m = nm;
  }
  l += (fexp2(z[0] - m) + fexp2(z[1] - m)) + (fexp2(z[2] - m) + fexp2(z[3] - m));
}

// ---- kernel 2: fused GEMM + online base-2 LSE ----------------------------
// grid 1024 = 32 row-blocks x 32 column chunks. 512 threads = 8 waves,
// 4 blocks/CU (33KB LDS, 64 VGPR). Wave owns 32 pred rows (2 n-subtiles);
// P frags resident in VGPRs. G tiles (32 x 256 bf16 = 16KB) double-buffered
// via global_load_lds (linear dest, inverse-XOR-swizzled source). ds_reads:
// dual base pointers (even/odd kk) + compile-time imm offsets.
// Swapped mfma(G,P): col=lane&15 -> pred, row -> gt; row-LSE lane-local.
__global__ __launch_bounds__(512, 8) void vmse_main(
    const unsigned short* __restrict__ Ah, const unsigned short* __restrict__ Bh,
    const float* __restrict__ ghs, float* __restrict__ partial)
{
  __shared__ unsigned short lds[2][32 * ND];   // 2 x 16 KB
  __shared__ float lds_ghs[256];               // chunk's (negated) offsets
  const int tid = threadIdx.x;
  const int lane = tid & 63;
  const int wid = tid >> 6;
  const int rb = blockIdx.x & 31;     // row block (256 rows)
  const int ch = blockIdx.x >> 5;     // column chunk (256 cols)
  const int r15 = lane & 15;
  const int hi = lane >> 4;
  const int j0 = ch * 256;

  // P fragments (pre-scaled): B-operand layout: n = lane&15, k = hi*8 + e
  short8 pf[2][8];
  #pragma unroll
  for (int ns = 0; ns < 2; ++ns) {
    const unsigned short* prow =
        Ah + (size_t)((rb * 256) + (wid * 32) + (ns * 16) + r15) * ND + hi * 8;
    #pragma unroll
    for (int kk = 0; kk < 8; ++kk)
      pf[ns][kk] = *(const short8*)(prow + kk * 32);
  }

  if (tid < 256) lds_ghs[tid] = ghs[j0 + tid];

  // dual-base LDS read pointers (even kk / odd kk), per buffer
  const int rbit = (r15 >> 2) & 1;
  const int h2 = hi ^ (r15 & 3);
  const char* ldsc = (const char*)&lds[0][0];
  const char* pE0 = ldsc + (r15 * 512 + h2 * 16 + rbit * 64);
  const char* pO0 = ldsc + (r15 * 512 + h2 * 16 + 64 - rbit * 64);
  const char* pE1 = pE0 + 16384;
  const char* pO1 = pO0 + 16384;

  // per-lane staging source pointers (t=0); +t*8192 ushorts per 32-row tile
  const unsigned short* srcb[2];
  #pragma unroll
  for (int i = 0; i < 2; ++i) {
    const int qq = wid * 2 + i;
    const int r = 2 * qq + (lane >> 5);
    const int cg = (lane & 31) ^ (r & 7);
    srcb[i] = Bh + (size_t)(j0 + r) * ND + cg * 8;
  }

  #define STAGE(buf, t)                                                      \
    {                                                                        \
      _Pragma("unroll")                                                      \
      for (int i = 0; i < 2; ++i)                                            \
        __builtin_amdgcn_global_load_lds(                                    \
            (const AS1 unsigned int*)(srcb[i] + (t) * 8192),                 \
            (AS3 unsigned int*)&lds[buf][(wid * 2 + i) * 512], 16, 0, 0);    \
    }

  float m2[2], l2[2];
  #pragma unroll
  for (int ns = 0; ns < 2; ++ns) { m2[ns] = -3.0e38f; l2[ns] = 0.0f; }

  // one 32-col tile: 2 ms-subtiles of {acc init from LDS, 16 MFMA, epilogue}
  #define COMPUTE(pE, pO, gp)                                                \
    {                                                                        \
      _Pragma("unroll")                                                      \
      for (int ms = 0; ms < 2; ++ms) {                                       \
        const char* gpm = (gp) + ms * 64 + hi * 16;                          \
        f32x4 a0 = *(const f32x4*)gpm;                                       \
        f32x4 a1 = a0;                                                       \
        __builtin_amdgcn_s_setprio(1);                                       \
        _Pragma("unroll")                                                    \
        for (int kk = 0; kk < 8; ++kk) {                                     \
          const short8 gf = (kk & 1)                                         \
              ? *(const short8*)((pO) + ms * 8192 + (kk - 1) * 64)           \
              : *(const short8*)((pE) + ms * 8192 + kk * 64);                \
          a0 = __builtin_amdgcn_mfma_f32_16x16x32_bf16(gf, pf[0][kk], a0, 0, 0, 0); \
          a1 = __builtin_amdgcn_mfma_f32_16x16x32_bf16(gf, pf[1][kk], a1, 0, 0, 0); \
        }                                                                    \
        __builtin_amdgcn_s_setprio(0);                                       \
        epi(a0, m2[0], l2[0]);                                               \
        epi(a1, m2[1], l2[1]);                                               \
      }                                                                      \
    }

  STAGE(0, 0);
  __syncthreads();   // tile 0 + lds_ghs ready

  const char* gp = (const char*)lds_ghs;
  for (int tt = 0; tt < 4; ++tt) {
    const int t = 2 * tt;
    STAGE(1, t + 1);                   // prefetch, stays in flight
    COMPUTE(pE0, pO0, gp);
    gp += 128;
    __syncthreads();                   // prefetch landed; buf0 free
    if (t + 2 < 8) STAGE(0, t + 2);
    COMPUTE(pE1, pO1, gp);
    gp += 128;
    __syncthreads();                   // prefetch landed; buf1 free
  }

  // combine lanes {i, i+16, i+32, i+48} (same pred row), write partial LSE
  #pragma unroll
  for (int ns = 0; ns < 2; ++ns) {
    float m = m2[ns], l = l2[ns];
    #pragma unroll
    for (int off = 16; off <= 32; off <<= 1) {
      const float om = __shfl_xor(m, off);
      const float ol = __shfl_xor(l, off);
      const float nm = fmaxf(m, om);
      l = l * fexp2(m - nm) + ol * fexp2(om - nm);
      m = nm;
    }
    if (hi == 0) {
      const int row = rb * 256 + wid * 32 + ns * 16 + r15;
      partial[row * NCHUNK + ch] = m + log2f(l);
    }
  }
}

// ---- kernel 3: per-row combine of chunk partials + diagonal --------------
__global__ __launch_bounds__(256) void vmse_combine(
    const float* __restrict__ partial, const float* __restrict__ diag,
    const float* __restrict__ gnorm, const float* __restrict__ sigma,
    float* __restrict__ bsum)
{
  const int r = blockIdx.x * 256 + threadIdx.x;
  const float nv = sigma[0] * sigma[0];
  float p[NCHUNK];
  float M = -3.0e38f;
  #pragma unroll
  for (int c = 0; c < NCHUNK; ++c) { p[c] = partial[r * NCHUNK + c]; M = fmaxf(M, p[c]); }
  float ssum = 0.f;
  #pragma unroll
  for (int c = 0; c < NCHUNK; ++c) ssum += exp2f(p[c] - M);
  const float lse2 = M + log2f(ssum);          // base-2 LSE of z*log2e
  const float zii = (diag[r] - 0.5f * gnorm[r]) / nv;
  float contrib = LN2F * lse2 - zii;           // lse_e - z_ii
  #pragma unroll
  for (int off = 1; off < 64; off <<= 1) contrib += __shfl_xor(contrib, off);
  __shared__ float wsum[4];
  if ((threadIdx.x & 63) == 0) wsum[threadIdx.x >> 6] = contrib;
  __syncthreads();
  if (threadIdx.x == 0)
    bsum[blockIdx.x] = (wsum[0] + wsum[1]) + (wsum[2] + wsum[3]);
}

// ---- kernel 4: deterministic finalize ------------------------------------
__global__ __launch_bounds__(64) void vmse_final(
    const float* __restrict__ bsum, const float* __restrict__ sigma,
    float* __restrict__ out)
{
  const int lane = threadIdx.x;
  float v = (lane < 32) ? bsum[lane] : 0.f;
  #pragma unroll
  for (int off = 1; off < 64; off <<= 1) v += __shfl_xor(v, off);
  if (lane == 0) {
    const float nv = sigma[0] * sigma[0];
    out[0] = v * (2.0f * nv / (float)NB);
  }
}

extern "C" void kernel_launch(void* const* d_in, const int* in_sizes, int n_in,
                              void* d_out, int out_size, void* d_ws, size_t ws_size,
                              hipStream_t stream)
{
  const float* pred  = (const float*)d_in[0];
  const float* gt    = (const float*)d_in[1];
  const float* sigma = (const float*)d_in[2];
  char* ws = (char*)d_ws;
  // ws: Ah 4MB | Bh 4MB | gnorm 32KB | diag 32KB | ghs 32KB | partial 1MB | bsum
  unsigned short* Ah = (unsigned short*)(ws);
  unsigned short* Bh = (unsigned short*)(ws + (4u << 20));
  float* gnorm   = (float*)(ws + (8u << 20));
  float* diag    = (float*)(ws + (8u << 20) + (32u << 10));
  float* ghs     = (float*)(ws + (8u << 20) + (64u << 10));
  float* partial = (float*)(ws + (8u << 20) + (96u << 10));
  float* bsum    = (float*)(ws + (8u << 20) + (96u << 10) + (1u << 20));

  vmse_prep<<<NB / 4, 256, 0, stream>>>(pred, gt, sigma, Ah, Bh, diag, gnorm, ghs);
  vmse_main<<<32 * NCHUNK, 512, 0, stream>>>(Ah, Bh, ghs, partial);
  vmse_combine<<<NB / 256, 256, 0, stream>>>(partial, diag, gnorm, sigma, bsum);
  vmse_final<<<1, 64, 0, stream>>>(bsum, sigma, (float*)d_out);
}

// Round 8
// 59.297 us; speedup vs baseline: 3.7897x; 3.7897x over previous
//
#include <hip/hip_runtime.h>

// InfoNCE/contrastive MVN loss:
// loss = mean_i( LSE_j((p_i.g_j - 0.5|g_j|^2)/nv) - (p_i.g_i - 0.5|g_i|^2)/nv ) * 2nv
// B = 8192, D = 256, fp32 inputs, scalar fp32 output.
// Main kernel: bf16 MFMA GEMM (P pre-scaled by s=log2e/nv) fused with online
// base-2 LSE. 32-row G tiles double-buffered via global_load_lds (33KB LDS ->
// 4 blocks/CU from LDS alone), launch_bounds(512,4) so VGPR stays at 64 (no
// spill). Dual-base imm-offset ds_reads, acc init from LDS, raw v_exp_f32,
// setprio around MFMA cluster.

typedef short short8 __attribute__((ext_vector_type(8)));
typedef float f32x4 __attribute__((ext_vector_type(4)));

#define LN2F 0.6931471805599453f
#define LOG2EF 1.4426950408889634f
#define NB 8192
#define ND 256
#define NCHUNK 32   // column chunks; chunk = 256 cols = 8 tiles of 32

#define AS1 __attribute__((address_space(1)))
#define AS3 __attribute__((address_space(3)))

__device__ __forceinline__ unsigned short f2bf(float f) {
  unsigned u = __float_as_uint(f);
  u += 0x7FFFu + ((u >> 16) & 1u);   // round-to-nearest-even
  return (unsigned short)(u >> 16);
}

__device__ __forceinline__ float fexp2(float x) {
#if __has_builtin(__builtin_amdgcn_exp2f)
  return __builtin_amdgcn_exp2f(x);   // raw v_exp_f32
#else
  float r;
  asm("v_exp_f32 %0, %1\n\ts_nop 1" : "=v"(r) : "v"(x));
  return r;
#endif
}

// ---- kernel 1: convert to bf16 (P pre-scaled) + exact fp32 row stats -----
__global__ __launch_bounds__(256) void vmse_prep(
    const float* __restrict__ pred, const float* __restrict__ gt,
    const float* __restrict__ sigma,
    unsigned short* __restrict__ Ah, unsigned short* __restrict__ Bh,
    float* __restrict__ diag, float* __restrict__ gnorm,
    float* __restrict__ ghs)
{
  const float nv = sigma[0] * sigma[0];
  const float s = LOG2EF / nv;
  const int row = blockIdx.x * 4 + (threadIdx.x >> 6);
  const int lane = threadIdx.x & 63;
  const float4 p = *(const float4*)(pred + row * ND + lane * 4);
  const float4 g = *(const float4*)(gt   + row * ND + lane * 4);
  ushort4 pa, ga;
  pa.x = f2bf(p.x * s); pa.y = f2bf(p.y * s);
  pa.z = f2bf(p.z * s); pa.w = f2bf(p.w * s);
  ga.x = f2bf(g.x); ga.y = f2bf(g.y); ga.z = f2bf(g.z); ga.w = f2bf(g.w);
  *(ushort4*)(Ah + row * ND + lane * 4) = pa;
  *(ushort4*)(Bh + row * ND + lane * 4) = ga;
  float dd = p.x * g.x + p.y * g.y + p.z * g.z + p.w * g.w;
  float gg = g.x * g.x + g.y * g.y + g.z * g.z + g.w * g.w;
  #pragma unroll
  for (int off = 1; off < 64; off <<= 1) {
    dd += __shfl_xor(dd, off);
    gg += __shfl_xor(gg, off);
  }
  if (lane == 0) {
    diag[row] = dd;
    gnorm[row] = gg;
    ghs[row] = -0.5f * s * gg;   // NEGATED base-2 logit offset (acc init)
  }
}

// per-4-logit online LSE epilogue
__device__ __forceinline__ void epi(const f32x4 z, float& m, float& l) {
  const float tmax = fmaxf(fmaxf(z[0], z[1]), fmaxf(z[2], z[3]));
  if (__any(tmax > m + 8.0f)) {      // T13 defer-max, rarely taken
    const float nm = fmaxf(m, tmax);
    l *= fexp2(m - nm);
    m = nm;
  }
  l += (fexp2(z[0] - m) + fexp2(z[1] - m)) + (fexp2(z[2] - m) + fexp2(z[3] - m));
}

// ---- kernel 2: fused GEMM + online base-2 LSE ----------------------------
// grid 1024 = 32 row-blocks x 32 column chunks. 512 threads = 8 waves.
// LDS 33KB -> 4 blocks/CU (hardware-scheduled); launch_bounds(512,4) keeps
// the VGPR cap at 128 so the natural 64-VGPR allocation survives (r7 lesson:
// (512,8) clamps to 32 VGPR and spills catastrophically).
// Wave owns 32 pred rows (2 n-subtiles); P frags resident in VGPRs. G tiles
// (32 x 256 bf16 = 16KB) double-buffered via global_load_lds (linear dest,
// inverse-XOR-swizzled source). ds_reads: dual base pointers (even/odd kk) +
// compile-time imm offsets.
// Swapped mfma(G,P): col=lane&15 -> pred, row -> gt; row-LSE lane-local.
__global__ __launch_bounds__(512, 4) void vmse_main(
    const unsigned short* __restrict__ Ah, const unsigned short* __restrict__ Bh,
    const float* __restrict__ ghs, float* __restrict__ partial)
{
  __shared__ unsigned short lds[2][32 * ND];   // 2 x 16 KB
  __shared__ float lds_ghs[256];               // chunk's (negated) offsets
  const int tid = threadIdx.x;
  const int lane = tid & 63;
  const int wid = tid >> 6;
  const int rb = blockIdx.x & 31;     // row block (256 rows)
  const int ch = blockIdx.x >> 5;     // column chunk (256 cols)
  const int r15 = lane & 15;
  const int hi = lane >> 4;
  const int j0 = ch * 256;

  // P fragments (pre-scaled): B-operand layout: n = lane&15, k = hi*8 + e
  short8 pf[2][8];
  #pragma unroll
  for (int ns = 0; ns < 2; ++ns) {
    const unsigned short* prow =
        Ah + (size_t)((rb * 256) + (wid * 32) + (ns * 16) + r15) * ND + hi * 8;
    #pragma unroll
    for (int kk = 0; kk < 8; ++kk)
      pf[ns][kk] = *(const short8*)(prow + kk * 32);
  }

  if (tid < 256) lds_ghs[tid] = ghs[j0 + tid];

  // dual-base LDS read pointers (even kk / odd kk), per buffer
  const int rbit = (r15 >> 2) & 1;
  const int h2 = hi ^ (r15 & 3);
  const char* ldsc = (const char*)&lds[0][0];
  const char* pE0 = ldsc + (r15 * 512 + h2 * 16 + rbit * 64);
  const char* pO0 = ldsc + (r15 * 512 + h2 * 16 + 64 - rbit * 64);
  const char* pE1 = pE0 + 16384;
  const char* pO1 = pO0 + 16384;

  // per-lane staging source pointers (t=0); +t*8192 ushorts per 32-row tile
  const unsigned short* srcb[2];
  #pragma unroll
  for (int i = 0; i < 2; ++i) {
    const int qq = wid * 2 + i;
    const int r = 2 * qq + (lane >> 5);
    const int cg = (lane & 31) ^ (r & 7);
    srcb[i] = Bh + (size_t)(j0 + r) * ND + cg * 8;
  }

  #define STAGE(buf, t)                                                      \
    {                                                                        \
      _Pragma("unroll")                                                      \
      for (int i = 0; i < 2; ++i)                                            \
        __builtin_amdgcn_global_load_lds(                                    \
            (const AS1 unsigned int*)(srcb[i] + (t) * 8192),                 \
            (AS3 unsigned int*)&lds[buf][(wid * 2 + i) * 512], 16, 0, 0);    \
    }

  float m2[2], l2[2];
  #pragma unroll
  for (int ns = 0; ns < 2; ++ns) { m2[ns] = -3.0e38f; l2[ns] = 0.0f; }

  // one 32-col tile: 2 ms-subtiles of {acc init from LDS, 16 MFMA, epilogue}
  #define COMPUTE(pE, pO, gp)                                                \
    {                                                                        \
      _Pragma("unroll")                                                      \
      for (int ms = 0; ms < 2; ++ms) {                                       \
        const char* gpm = (gp) + ms * 64 + hi * 16;                          \
        f32x4 a0 = *(const f32x4*)gpm;                                       \
        f32x4 a1 = a0;                                                       \
        __builtin_amdgcn_s_setprio(1);                                       \
        _Pragma("unroll")                                                    \
        for (int kk = 0; kk < 8; ++kk) {                                     \
          const short8 gf = (kk & 1)                                         \
              ? *(const short8*)((pO) + ms * 8192 + (kk - 1) * 64)           \
              : *(const short8*)((pE) + ms * 8192 + kk * 64);                \
          a0 = __builtin_amdgcn_mfma_f32_16x16x32_bf16(gf, pf[0][kk], a0, 0, 0, 0); \
          a1 = __builtin_amdgcn_mfma_f32_16x16x32_bf16(gf, pf[1][kk], a1, 0, 0, 0); \
        }                                                                    \
        __builtin_amdgcn_s_setprio(0);                                       \
        epi(a0, m2[0], l2[0]);                                               \
        epi(a1, m2[1], l2[1]);                                               \
      }                                                                      \
    }

  STAGE(0, 0);
  __syncthreads();   // tile 0 + lds_ghs ready

  const char* gp = (const char*)lds_ghs;
  for (int tt = 0; tt < 4; ++tt) {
    const int t = 2 * tt;
    STAGE(1, t + 1);                   // prefetch, stays in flight
    COMPUTE(pE0, pO0, gp);
    gp += 128;
    __syncthreads();                   // prefetch landed; buf0 free
    if (t + 2 < 8) STAGE(0, t + 2);
    COMPUTE(pE1, pO1, gp);
    gp += 128;
    __syncthreads();                   // prefetch landed; buf1 free
  }

  // combine lanes {i, i+16, i+32, i+48} (same pred row), write partial LSE
  #pragma unroll
  for (int ns = 0; ns < 2; ++ns) {
    float m = m2[ns], l = l2[ns];
    #pragma unroll
    for (int off = 16; off <= 32; off <<= 1) {
      const float om = __shfl_xor(m, off);
      const float ol = __shfl_xor(l, off);
      const float nm = fmaxf(m, om);
      l = l * fexp2(m - nm) + ol * fexp2(om - nm);
      m = nm;
    }
    if (hi == 0) {
      const int row = rb * 256 + wid * 32 + ns * 16 + r15;
      partial[row * NCHUNK + ch] = m + log2f(l);
    }
  }
}

// ---- kernel 3: per-row combine of chunk partials + diagonal --------------
__global__ __launch_bounds__(256) void vmse_combine(
    const float* __restrict__ partial, const float* __restrict__ diag,
    const float* __restrict__ gnorm, const float* __restrict__ sigma,
    float* __restrict__ bsum)
{
  const int r = blockIdx.x * 256 + threadIdx.x;
  const float nv = sigma[0] * sigma[0];
  float p[NCHUNK];
  float M = -3.0e38f;
  #pragma unroll
  for (int c = 0; c < NCHUNK; ++c) { p[c] = partial[r * NCHUNK + c]; M = fmaxf(M, p[c]); }
  float ssum = 0.f;
  #pragma unroll
  for (int c = 0; c < NCHUNK; ++c) ssum += exp2f(p[c] - M);
  const float lse2 = M + log2f(ssum);          // base-2 LSE of z*log2e
  const float zii = (diag[r] - 0.5f * gnorm[r]) / nv;
  float contrib = LN2F * lse2 - zii;           // lse_e - z_ii
  #pragma unroll
  for (int off = 1; off < 64; off <<= 1) contrib += __shfl_xor(contrib, off);
  __shared__ float wsum[4];
  if ((threadIdx.x & 63) == 0) wsum[threadIdx.x >> 6] = contrib;
  __syncthreads();
  if (threadIdx.x == 0)
    bsum[blockIdx.x] = (wsum[0] + wsum[1]) + (wsum[2] + wsum[3]);
}

// ---- kernel 4: deterministic finalize ------------------------------------
__global__ __launch_bounds__(64) void vmse_final(
    const float* __restrict__ bsum, const float* __restrict__ sigma,
    float* __restrict__ out)
{
  const int lane = threadIdx.x;
  float v = (lane < 32) ? bsum[lane] : 0.f;
  #pragma unroll
  for (int off = 1; off < 64; off <<= 1) v += __shfl_xor(v, off);
  if (lane == 0) {
    const float nv = sigma[0] * sigma[0];
    out[0] = v * (2.0f * nv / (float)NB);
  }
}

extern "C" void kernel_launch(void* const* d_in, const int* in_sizes, int n_in,
                              void* d_out, int out_size, void* d_ws, size_t ws_size,
                              hipStream_t stream)
{
  const float* pred  = (const float*)d_in[0];
  const float* gt    = (const float*)d_in[1];
  const float* sigma = (const float*)d_in[2];
  char* ws = (char*)d_ws;
  // ws: Ah 4MB | Bh 4MB | gnorm 32KB | diag 32KB | ghs 32KB | partial 1MB | bsum
  unsigned short* Ah = (unsigned short*)(ws);
  unsigned short* Bh = (unsigned short*)(ws + (4u << 20));
  float* gnorm   = (float*)(ws + (8u << 20));
  float* diag    = (float*)(ws + (8u << 20) + (32u << 10));
  float* ghs     = (float*)(ws + (8u << 20) + (64u << 10));
  float* partial = (float*)(ws + (8u << 20) + (96u << 10));
  float* bsum    = (float*)(ws + (8u << 20) + (96u << 10) + (1u << 20));

  vmse_prep<<<NB / 4, 256, 0, stream>>>(pred, gt, sigma, Ah, Bh, diag, gnorm, ghs);
  vmse_main<<<32 * NCHUNK, 512, 0, stream>>>(Ah, Bh, ghs, partial);
  vmse_combine<<<NB / 256, 256, 0, stream>>>(partial, diag, gnorm, sigma, bsum);
  vmse_final<<<1, 64, 0, stream>>>(bsum, sigma, (float*)d_out);
}

// Round 9
// 46.825 us; speedup vs baseline: 4.7991x; 1.2664x over previous
//
#include <hip/hip_runtime.h>
#include <hip/hip_fp8.h>

// InfoNCE/contrastive MVN loss:
// loss = mean_i( LSE_j((p_i.g_j - 0.5|g_j|^2)/nv) - (p_i.g_i - 0.5|g_i|^2)/nv ) * 2nv
// B = 8192, D = 256, fp32 inputs, scalar fp32 output.
// Main kernel: fp8-e4m3 MFMA GEMM (P pre-scaled by s=log2e/nv) fused with
// online base-2 LSE. fp8 halves LDS-pipe traffic (r8 analysis: LDS 20.5us >
// MFMA floor 16.6us was the binding pipe). Frag-pair-major fp8 layout so one
// ds_read_b128 = 2 k-step fragments. Diagonal + |g|^2 terms stay exact fp32.

typedef float f32x4 __attribute__((ext_vector_type(4)));
typedef long llong2 __attribute__((ext_vector_type(2)));

#define LN2F 0.6931471805599453f
#define LOG2EF 1.4426950408889634f
#define NB 8192
#define ND 256
#define NCHUNK 32   // column chunks; chunk = 256 cols = 8 tiles of 32

#define AS1 __attribute__((address_space(1)))
#define AS3 __attribute__((address_space(3)))

__device__ __forceinline__ float fexp2(float x) {
#if __has_builtin(__builtin_amdgcn_exp2f)
  return __builtin_amdgcn_exp2f(x);   // raw v_exp_f32
#else
  float r;
  asm("v_exp_f32 %0, %1\n\ts_nop 1" : "=v"(r) : "v"(x));
  return r;
#endif
}

__device__ __forceinline__ int pack4_fp8(float a, float b, float c, float d) {
#if __has_builtin(__builtin_amdgcn_cvt_pk_fp8_f32)
  int w = __builtin_amdgcn_cvt_pk_fp8_f32(a, b, 0, false);
  w = __builtin_amdgcn_cvt_pk_fp8_f32(c, d, w, true);
  return w;
#else
  unsigned b0 = __hip_fp8_e4m3(a).__x, b1 = __hip_fp8_e4m3(b).__x;
  unsigned b2 = __hip_fp8_e4m3(c).__x, b3 = __hip_fp8_e4m3(d).__x;
  return (int)(b0 | (b1 << 8) | (b2 << 16) | (b3 << 24));
#endif
}

// ---- kernel 1: convert to fp8 (P pre-scaled, frag-pair-major layout) -----
// layout: byte pos(k) = (k>>6)*64 + ((k&31)>>3)*16 + ((k>>5)&1)*8 + (k&7)
// so a b128 read at kk2*64+hi*16 yields frags (kk=2*kk2, hi) and (2*kk2+1, hi).
__global__ __launch_bounds__(256) void vmse_prep(
    const float* __restrict__ pred, const float* __restrict__ gt,
    const float* __restrict__ sigma,
    unsigned char* __restrict__ Ah, unsigned char* __restrict__ Bh,
    float* __restrict__ diag, float* __restrict__ gnorm,
    float* __restrict__ ghs)
{
  const float nv = sigma[0] * sigma[0];
  const float s = LOG2EF / nv;
  const int row = blockIdx.x * 4 + (threadIdx.x >> 6);
  const int l = threadIdx.x & 63;
  const float4 p = *(const float4*)(pred + row * ND + l * 4);
  const float4 g = *(const float4*)(gt   + row * ND + l * 4);
  const int pw = pack4_fp8(p.x * s, p.y * s, p.z * s, p.w * s);
  const int gw = pack4_fp8(g.x, g.y, g.z, g.w);
  // lane l covers k = 4l..4l+3 -> pos = (l>>4)*64 + ((l&7)>>1)*16 + ((l>>3)&1)*8 + (l&1)*4
  const int pos = (l >> 4) * 64 + ((l & 7) >> 1) * 16 + ((l >> 3) & 1) * 8 + (l & 1) * 4;
  *(int*)(Ah + row * ND + pos) = pw;
  *(int*)(Bh + row * ND + pos) = gw;
  float dd = p.x * g.x + p.y * g.y + p.z * g.z + p.w * g.w;
  float gg = g.x * g.x + g.y * g.y + g.z * g.z + g.w * g.w;
  #pragma unroll
  for (int off = 1; off < 64; off <<= 1) {
    dd += __shfl_xor(dd, off);
    gg += __shfl_xor(gg, off);
  }
  if (l == 0) {
    diag[row] = dd;                // exact fp32 p_i . g_i
    gnorm[row] = gg;
    ghs[row] = -0.5f * s * gg;     // NEGATED base-2 logit offset (acc init)
  }
}

// per-4-logit online LSE epilogue
__device__ __forceinline__ void epi(const f32x4 z, float& m, float& l) {
  const float tmax = fmaxf(fmaxf(z[0], z[1]), fmaxf(z[2], z[3]));
  if (__any(tmax > m + 8.0f)) {      // T13 defer-max, rarely taken
    const float nm = fmaxf(m, tmax);
    l *= fexp2(m - nm);
    m = nm;
  }
  l += (fexp2(z[0] - m) + fexp2(z[1] - m)) + (fexp2(z[2] - m) + fexp2(z[3] - m));
}

// ---- kernel 2: fused fp8 GEMM + online base-2 LSE ------------------------
// grid 2048 = 64 row-blocks x 32 column chunks. 256 threads = 4 waves.
// Wave owns 32 pred rows (2 n-subtiles, pf = 32 VGPR). G tiles (32 rows x
// 256 B fp8 = 8KB) double-buffered via global_load_lds (linear dest,
// inverse-XOR-swizzled source; chunk c at LDS holds global chunk c^(row&7)).
// ds_read_b128 = 2 fp8 frags; dual-base pointers absorb the XOR:
//  addr = r15*256 + (hi^r7lo)*16 + ((kk2^r7hi)... ) -> pE/pO + {0,128} imm.
// Swapped mfma(G,P): col=lane&15 -> pred, row -> gt; row-LSE lane-local.
__global__ __launch_bounds__(256, 4) void vmse_main(
    const unsigned char* __restrict__ Ah, const unsigned char* __restrict__ Bh,
    const float* __restrict__ ghs, float* __restrict__ partial)
{
  __shared__ unsigned char lds[2][32 * 256];   // 2 x 8 KB
  __shared__ float lds_ghs[256];               // chunk's (negated) offsets
  const int tid = threadIdx.x;
  const int lane = tid & 63;
  const int wid = tid >> 6;
  const int rb = blockIdx.x & 63;     // row block (128 rows)
  const int ch = blockIdx.x >> 6;     // column chunk (256 cols)
  const int r15 = lane & 15;
  const int hi = lane >> 4;
  const int j0 = ch * 256;

  // P fragments (pre-scaled fp8): B-operand: col = lane&15, k = hi*8+e per kk
  long pf[2][8];
  #pragma unroll
  for (int ns = 0; ns < 2; ++ns) {
    const unsigned char* prow =
        Ah + (size_t)((rb * 128) + (wid * 32) + (ns * 16) + r15) * ND;
    #pragma unroll
    for (int kk2 = 0; kk2 < 4; ++kk2) {
      const llong2 v = *(const llong2*)(prow + kk2 * 64 + hi * 16);
      pf[ns][2 * kk2] = v[0];
      pf[ns][2 * kk2 + 1] = v[1];
    }
  }

  lds_ghs[tid] = ghs[j0 + tid];

  // dual-base LDS read pointers: chunk (kk2*4+hi) ^ (r15&7), split r7 = r7hi*4+r7lo
  const int r7 = r15 & 7;
  const int r7lo = r7 & 3, r7hi = r7 >> 2;
  const int h2 = hi ^ r7lo;
  const char* base = (const char*)&lds[0][0] + r15 * 256 + h2 * 16;
  const char* pE = base + r7hi * 64;          // kk2 even: +0, +128
  const char* pO = base + 64 - r7hi * 64;     // kk2 odd:  +0, +128

  // staging source pointers (t=0); +t*8192 bytes per 32-row tile
  const unsigned char* srcb[2];
  #pragma unroll
  for (int i = 0; i < 2; ++i) {
    const int q = wid * 2 + i;
    const int r = q * 4 + (lane >> 4);
    const int cg = (lane & 15) ^ (r & 7);
    srcb[i] = Bh + (size_t)(j0 + r) * ND + cg * 16;
  }

  #define STAGE(buf, t)                                                      \
    {                                                                        \
      _Pragma("unroll")                                                      \
      for (int i = 0; i < 2; ++i)                                            \
        __builtin_amdgcn_global_load_lds(                                    \
            (const AS1 unsigned int*)(srcb[i] + (t) * 8192),                 \
            (AS3 unsigned int*)&lds[buf][(wid * 2 + i) * 1024], 16, 0, 0);   \
    }

  float m2[2], l2[2];
  #pragma unroll
  for (int ns = 0; ns < 2; ++ns) { m2[ns] = -3.0e38f; l2[ns] = 0.0f; }

  // one 32-col tile: 2 ms-subtiles of {acc init, 4 b128 reads, 16 MFMA, epi}
  #define COMPUTE(PE, PO, gp)                                                \
    {                                                                        \
      _Pragma("unroll")                                                      \
      for (int ms = 0; ms < 2; ++ms) {                                       \
        const f32x4 gv = *(const f32x4*)((gp) + ms * 64 + hi * 16);          \
        f32x4 a0 = gv;                                                       \
        f32x4 a1 = gv;                                                       \
        const llong2 gA = *(const llong2*)((PE) + ms * 4096);                \
        const llong2 gB = *(const llong2*)((PO) + ms * 4096);                \
        const llong2 gC = *(const llong2*)((PE) + ms * 4096 + 128);          \
        const llong2 gD = *(const llong2*)((PO) + ms * 4096 + 128);          \
        const long gf[8] = {gA[0], gA[1], gB[0], gB[1],                      \
                            gC[0], gC[1], gD[0], gD[1]};                     \
        __builtin_amdgcn_s_setprio(1);                                       \
        _Pragma("unroll")                                                    \
        for (int kk = 0; kk < 8; ++kk) {                                     \
          a0 = __builtin_amdgcn_mfma_f32_16x16x32_fp8_fp8(gf[kk], pf[0][kk], a0, 0, 0, 0); \
          a1 = __builtin_amdgcn_mfma_f32_16x16x32_fp8_fp8(gf[kk], pf[1][kk], a1, 0, 0, 0); \
        }                                                                    \
        __builtin_amdgcn_s_setprio(0);                                       \
        epi(a0, m2[0], l2[0]);                                               \
        epi(a1, m2[1], l2[1]);                                               \
      }                                                                      \
    }

  STAGE(0, 0);
  __syncthreads();   // tile 0 + lds_ghs ready

  const char* gp = (const char*)lds_ghs;
  for (int tt = 0; tt < 4; ++tt) {
    const int t = 2 * tt;
    STAGE(1, t + 1);                   // prefetch, stays in flight
    COMPUTE(pE, pO, gp);
    gp += 128;
    __syncthreads();                   // prefetch landed; buf0 free
    if (t + 2 < 8) STAGE(0, t + 2);
    COMPUTE(pE + 8192, pO + 8192, gp);
    gp += 128;
    __syncthreads();                   // prefetch landed; buf1 free
  }

  // combine lanes {i, i+16, i+32, i+48} (same pred row), write partial LSE
  #pragma unroll
  for (int ns = 0; ns < 2; ++ns) {
    float m = m2[ns], l = l2[ns];
    #pragma unroll
    for (int off = 16; off <= 32; off <<= 1) {
      const float om = __shfl_xor(m, off);
      const float ol = __shfl_xor(l, off);
      const float nm = fmaxf(m, om);
      l = l * fexp2(m - nm) + ol * fexp2(om - nm);
      m = nm;
    }
    if (hi == 0) {
      const int row = rb * 128 + wid * 32 + ns * 16 + r15;
      partial[row * NCHUNK + ch] = m + log2f(l);
    }
  }
}

// ---- kernel 3: per-row combine of chunk partials + diagonal --------------
__global__ __launch_bounds__(256) void vmse_combine(
    const float* __restrict__ partial, const float* __restrict__ diag,
    const float* __restrict__ gnorm, const float* __restrict__ sigma,
    float* __restrict__ bsum)
{
  const int r = blockIdx.x * 256 + threadIdx.x;
  const float nv = sigma[0] * sigma[0];
  float p[NCHUNK];
  float M = -3.0e38f;
  #pragma unroll
  for (int c = 0; c < NCHUNK; ++c) { p[c] = partial[r * NCHUNK + c]; M = fmaxf(M, p[c]); }
  float ssum = 0.f;
  #pragma unroll
  for (int c = 0; c < NCHUNK; ++c) ssum += exp2f(p[c] - M);
  const float lse2 = M + log2f(ssum);          // base-2 LSE of z*log2e
  const float zii = (diag[r] - 0.5f * gnorm[r]) / nv;
  float contrib = LN2F * lse2 - zii;           // lse_e - z_ii
  #pragma unroll
  for (int off = 1; off < 64; off <<= 1) contrib += __shfl_xor(contrib, off);
  __shared__ float wsum[4];
  if ((threadIdx.x & 63) == 0) wsum[threadIdx.x >> 6] = contrib;
  __syncthreads();
  if (threadIdx.x == 0)
    bsum[blockIdx.x] = (wsum[0] + wsum[1]) + (wsum[2] + wsum[3]);
}

// ---- kernel 4: deterministic finalize ------------------------------------
__global__ __launch_bounds__(64) void vmse_final(
    const float* __restrict__ bsum, const float* __restrict__ sigma,
    float* __restrict__ out)
{
  const int lane = threadIdx.x;
  float v = (lane < 32) ? bsum[lane] : 0.f;
  #pragma unroll
  for (int off = 1; off < 64; off <<= 1) v += __shfl_xor(v, off);
  if (lane == 0) {
    const float nv = sigma[0] * sigma[0];
    out[0] = v * (2.0f * nv / (float)NB);
  }
}

extern "C" void kernel_launch(void* const* d_in, const int* in_sizes, int n_in,
                              void* d_out, int out_size, void* d_ws, size_t ws_size,
                              hipStream_t stream)
{
  const float* pred  = (const float*)d_in[0];
  const float* gt    = (const float*)d_in[1];
  const float* sigma = (const float*)d_in[2];
  char* ws = (char*)d_ws;
  // ws: Ah 2MB | Bh 2MB | gnorm 32KB | diag 32KB | ghs 32KB | partial 1MB | bsum
  unsigned char* Ah = (unsigned char*)(ws);
  unsigned char* Bh = (unsigned char*)(ws + (2u << 20));
  float* gnorm   = (float*)(ws + (4u << 20));
  float* diag    = (float*)(ws + (4u << 20) + (32u << 10));
  float* ghs     = (float*)(ws + (4u << 20) + (64u << 10));
  float* partial = (float*)(ws + (4u << 20) + (96u << 10));
  float* bsum    = (float*)(ws + (4u << 20) + (96u << 10) + (1u << 20));

  vmse_prep<<<NB / 4, 256, 0, stream>>>(pred, gt, sigma, Ah, Bh, diag, gnorm, ghs);
  vmse_main<<<64 * NCHUNK, 256, 0, stream>>>(Ah, Bh, ghs, partial);
  vmse_combine<<<NB / 256, 256, 0, stream>>>(partial, diag, gnorm, sigma, bsum);
  vmse_final<<<1, 64, 0, stream>>>(bsum, sigma, (float*)d_out);
}

// Round 10
// 45.262 us; speedup vs baseline: 4.9648x; 1.0345x over previous
//
#include <hip/hip_runtime.h>
#include <hip/hip_fp8.h>

// InfoNCE/contrastive MVN loss:
// loss = mean_i( LSE_j((p_i.g_j - 0.5|g_j|^2)/nv) - (p_i.g_i - 0.5|g_i|^2)/nv ) * 2nv
// B = 8192, D = 256, fp32 inputs, scalar fp32 output.
// Main kernel: fp8-e4m3 MFMA GEMM (P pre-scaled by s=log2e/nv) fused with
// online base-2 LSE. Whole 64KB G-panel (256 cols x 256B) staged to LDS once
// per block -> ONE barrier total, zero barriers in the MFMA/epilogue stream
// (r9 analysis: 2-phase barrier structure held us at 46% of the MFMA bound).
// Frag-pair-major fp8 layout: one ds_read_b128 = 2 k-step fragments.

typedef float f32x4 __attribute__((ext_vector_type(4)));
typedef long llong2 __attribute__((ext_vector_type(2)));

#define LN2F 0.6931471805599453f
#define LOG2EF 1.4426950408889634f
#define NB 8192
#define ND 256
#define NCHUNK 32   // column chunks; chunk = 256 cols = 8 tiles of 32

#define AS1 __attribute__((address_space(1)))
#define AS3 __attribute__((address_space(3)))

__device__ __forceinline__ float fexp2(float x) {
#if __has_builtin(__builtin_amdgcn_exp2f)
  return __builtin_amdgcn_exp2f(x);   // raw v_exp_f32
#else
  float r;
  asm("v_exp_f32 %0, %1\n\ts_nop 1" : "=v"(r) : "v"(x));
  return r;
#endif
}

__device__ __forceinline__ int pack4_fp8(float a, float b, float c, float d) {
#if __has_builtin(__builtin_amdgcn_cvt_pk_fp8_f32)
  int w = __builtin_amdgcn_cvt_pk_fp8_f32(a, b, 0, false);
  w = __builtin_amdgcn_cvt_pk_fp8_f32(c, d, w, true);
  return w;
#else
  unsigned b0 = __hip_fp8_e4m3(a).__x, b1 = __hip_fp8_e4m3(b).__x;
  unsigned b2 = __hip_fp8_e4m3(c).__x, b3 = __hip_fp8_e4m3(d).__x;
  return (int)(b0 | (b1 << 8) | (b2 << 16) | (b3 << 24));
#endif
}

// ---- kernel 1: convert to fp8 (P pre-scaled, frag-pair-major layout) -----
// layout: byte pos(k) = (k>>6)*64 + ((k&31)>>3)*16 + ((k>>5)&1)*8 + (k&7)
// so a b128 read at kk2*64+hi*16 yields frags (kk=2*kk2, hi) and (2*kk2+1, hi).
__global__ __launch_bounds__(256) void vmse_prep(
    const float* __restrict__ pred, const float* __restrict__ gt,
    const float* __restrict__ sigma,
    unsigned char* __restrict__ Ah, unsigned char* __restrict__ Bh,
    float* __restrict__ diag, float* __restrict__ gnorm,
    float* __restrict__ ghs)
{
  const float nv = sigma[0] * sigma[0];
  const float s = LOG2EF / nv;
  const int row = blockIdx.x * 4 + (threadIdx.x >> 6);
  const int l = threadIdx.x & 63;
  const float4 p = *(const float4*)(pred + row * ND + l * 4);
  const float4 g = *(const float4*)(gt   + row * ND + l * 4);
  const int pw = pack4_fp8(p.x * s, p.y * s, p.z * s, p.w * s);
  const int gw = pack4_fp8(g.x, g.y, g.z, g.w);
  // lane l covers k = 4l..4l+3 -> pos = (l>>4)*64 + ((l&7)>>1)*16 + ((l>>3)&1)*8 + (l&1)*4
  const int pos = (l >> 4) * 64 + ((l & 7) >> 1) * 16 + ((l >> 3) & 1) * 8 + (l & 1) * 4;
  *(int*)(Ah + row * ND + pos) = pw;
  *(int*)(Bh + row * ND + pos) = gw;
  float dd = p.x * g.x + p.y * g.y + p.z * g.z + p.w * g.w;
  float gg = g.x * g.x + g.y * g.y + g.z * g.z + g.w * g.w;
  #pragma unroll
  for (int off = 1; off < 64; off <<= 1) {
    dd += __shfl_xor(dd, off);
    gg += __shfl_xor(gg, off);
  }
  if (l == 0) {
    diag[row] = dd;                // exact fp32 p_i . g_i
    gnorm[row] = gg;
    ghs[row] = -0.5f * s * gg;     // NEGATED base-2 logit offset (acc init)
  }
}

// per-4-logit online LSE epilogue
__device__ __forceinline__ void epi(const f32x4 z, float& m, float& l) {
  const float tmax = fmaxf(fmaxf(z[0], z[1]), fmaxf(z[2], z[3]));
  if (__any(tmax > m + 8.0f)) {      // T13 defer-max, rarely taken
    const float nm = fmaxf(m, tmax);
    l *= fexp2(m - nm);
    m = nm;
  }
  l += (fexp2(z[0] - m) + fexp2(z[1] - m)) + (fexp2(z[2] - m) + fexp2(z[3] - m));
}

// ---- kernel 2: fused fp8 GEMM + online base-2 LSE, one-barrier -----------
// grid 1024 = 32 row-blocks x 32 column chunks. 512 threads = 8 waves,
// 2 blocks/CU (66.5KB LDS). Block = 256 P-rows x 256 G-cols; wave owns 32
// rows (2 n-subtiles, pf = 32 VGPR). Whole G panel (8 tiles x 32 rows x
// 256B) staged via 8 global_load_lds/thread (linear dest, inverse-XOR-
// swizzled source: LDS chunk c of row r holds global chunk c^(r&7)); P-frag
// global loads overlap staging latency; ONE __syncthreads; then 256 MFMA +
// epilogues with zero barriers. ds_read_b128 = 2 fp8 frags; dual-base
// pointers absorb the XOR; tile loop = 4 iters x 2 tiles, +16KB ptr bump.
// Swapped mfma(G,P): col=lane&15 -> pred, row -> gt; row-LSE lane-local.
__global__ __launch_bounds__(512, 4) void vmse_main(
    const unsigned char* __restrict__ Ah, const unsigned char* __restrict__ Bh,
    const float* __restrict__ ghs, float* __restrict__ partial)
{
  __shared__ unsigned char lds[8][32 * 256];   // 64 KB: whole column chunk
  __shared__ float lds_ghs[256];               // chunk's (negated) offsets
  const int tid = threadIdx.x;
  const int lane = tid & 63;
  const int wid = tid >> 6;
  const int rb = blockIdx.x & 31;     // row block (256 rows)
  const int ch = blockIdx.x >> 5;     // column chunk (256 cols)
  const int r15 = lane & 15;
  const int hi = lane >> 4;
  const int j0 = ch * 256;

  // stage the whole 64KB panel: tile t -> lds[t]; per thread 1 instr/tile.
  // lane l: row r = wid*4 + (l>>4), global chunk (l&15)^(r&7); dest linear.
  {
    const int r = wid * 4 + (lane >> 4);
    const int cg = (lane & 15) ^ (r & 7);
    const unsigned char* src = Bh + (size_t)(j0 + r) * ND + cg * 16;
    #pragma unroll
    for (int t = 0; t < 8; ++t)
      __builtin_amdgcn_global_load_lds(
          (const AS1 unsigned int*)(src + t * 8192),
          (AS3 unsigned int*)&lds[t][wid * 1024], 16, 0, 0);
  }
  if (tid < 256) lds_ghs[tid] = ghs[j0 + tid];

  // P fragments (pre-scaled fp8) — global loads overlap the staging above
  long pf[2][8];
  #pragma unroll
  for (int ns = 0; ns < 2; ++ns) {
    const unsigned char* prow =
        Ah + (size_t)((rb * 256) + (wid * 32) + (ns * 16) + r15) * ND;
    #pragma unroll
    for (int kk2 = 0; kk2 < 4; ++kk2) {
      const llong2 v = *(const llong2*)(prow + kk2 * 64 + hi * 16);
      pf[ns][2 * kk2] = v[0];
      pf[ns][2 * kk2 + 1] = v[1];
    }
  }

  // dual-base LDS read pointers: chunk (kk2*4+hi) ^ (r15&7), r7 = r7hi*4+r7lo
  const int r7 = r15 & 7;
  const int r7lo = r7 & 3, r7hi = r7 >> 2;
  const int h2 = hi ^ r7lo;
  const char* base = (const char*)&lds[0][0] + r15 * 256 + h2 * 16;
  const char* pE = base + r7hi * 64;          // kk2 even: imm +0, +128
  const char* pO = base + 64 - r7hi * 64;     // kk2 odd:  imm +0, +128

  float m2[2], l2[2];
  #pragma unroll
  for (int ns = 0; ns < 2; ++ns) { m2[ns] = -3.0e38f; l2[ns] = 0.0f; }

  // one 32-col tile: 2 ms-subtiles of {acc init, 4 b128 reads, 16 MFMA, epi}
  #define COMPUTE(PE, PO, gp)                                                \
    {                                                                        \
      _Pragma("unroll")                                                      \
      for (int ms = 0; ms < 2; ++ms) {                                       \
        const f32x4 gv = *(const f32x4*)((gp) + ms * 64 + hi * 16);          \
        f32x4 a0 = gv;                                                       \
        f32x4 a1 = gv;                                                       \
        const llong2 gA = *(const llong2*)((PE) + ms * 4096);                \
        const llong2 gB = *(const llong2*)((PO) + ms * 4096);                \
        const llong2 gC = *(const llong2*)((PE) + ms * 4096 + 128);          \
        const llong2 gD = *(const llong2*)((PO) + ms * 4096 + 128);          \
        const long gf[8] = {gA[0], gA[1], gB[0], gB[1],                      \
                            gC[0], gC[1], gD[0], gD[1]};                     \
        __builtin_amdgcn_s_setprio(1);                                       \
        _Pragma("unroll")                                                    \
        for (int kk = 0; kk < 8; ++kk) {                                     \
          a0 = __builtin_amdgcn_mfma_f32_16x16x32_fp8_fp8(gf[kk], pf[0][kk], a0, 0, 0, 0); \
          a1 = __builtin_amdgcn_mfma_f32_16x16x32_fp8_fp8(gf[kk], pf[1][kk], a1, 0, 0, 0); \
        }                                                                    \
        __builtin_amdgcn_s_setprio(0);                                       \
        epi(a0, m2[0], l2[0]);                                               \
        epi(a1, m2[1], l2[1]);                                               \
      }                                                                      \
    }

  __syncthreads();   // the ONLY barrier: panel + ghs resident

  const char* pEc = pE;
  const char* pOc = pO;
  const char* gp = (const char*)lds_ghs;
  for (int tt = 0; tt < 4; ++tt) {
    COMPUTE(pEc, pOc, gp);                       // tile 2tt
    COMPUTE(pEc + 8192, pOc + 8192, gp + 128);   // tile 2tt+1
    pEc += 16384; pOc += 16384; gp += 256;
  }

  // combine lanes {i, i+16, i+32, i+48} (same pred row), write partial LSE
  #pragma unroll
  for (int ns = 0; ns < 2; ++ns) {
    float m = m2[ns], l = l2[ns];
    #pragma unroll
    for (int off = 16; off <= 32; off <<= 1) {
      const float om = __shfl_xor(m, off);
      const float ol = __shfl_xor(l, off);
      const float nm = fmaxf(m, om);
      l = l * fexp2(m - nm) + ol * fexp2(om - nm);
      m = nm;
    }
    if (hi == 0) {
      const int row = rb * 256 + wid * 32 + ns * 16 + r15;
      partial[row * NCHUNK + ch] = m + log2f(l);
    }
  }
}

// ---- kernel 3: per-row combine of chunk partials + diagonal --------------
__global__ __launch_bounds__(256) void vmse_combine(
    const float* __restrict__ partial, const float* __restrict__ diag,
    const float* __restrict__ gnorm, const float* __restrict__ sigma,
    float* __restrict__ bsum)
{
  const int r = blockIdx.x * 256 + threadIdx.x;
  const float nv = sigma[0] * sigma[0];
  float p[NCHUNK];
  float M = -3.0e38f;
  #pragma unroll
  for (int c = 0; c < NCHUNK; ++c) { p[c] = partial[r * NCHUNK + c]; M = fmaxf(M, p[c]); }
  float ssum = 0.f;
  #pragma unroll
  for (int c = 0; c < NCHUNK; ++c) ssum += exp2f(p[c] - M);
  const float lse2 = M + log2f(ssum);          // base-2 LSE of z*log2e
  const float zii = (diag[r] - 0.5f * gnorm[r]) / nv;
  float contrib = LN2F * lse2 - zii;           // lse_e - z_ii
  #pragma unroll
  for (int off = 1; off < 64; off <<= 1) contrib += __shfl_xor(contrib, off);
  __shared__ float wsum[4];
  if ((threadIdx.x & 63) == 0) wsum[threadIdx.x >> 6] = contrib;
  __syncthreads();
  if (threadIdx.x == 0)
    bsum[blockIdx.x] = (wsum[0] + wsum[1]) + (wsum[2] + wsum[3]);
}

// ---- kernel 4: deterministic finalize ------------------------------------
__global__ __launch_bounds__(64) void vmse_final(
    const float* __restrict__ bsum, const float* __restrict__ sigma,
    float* __restrict__ out)
{
  const int lane = threadIdx.x;
  float v = (lane < 32) ? bsum[lane] : 0.f;
  #pragma unroll
  for (int off = 1; off < 64; off <<= 1) v += __shfl_xor(v, off);
  if (lane == 0) {
    const float nv = sigma[0] * sigma[0];
    out[0] = v * (2.0f * nv / (float)NB);
  }
}

extern "C" void kernel_launch(void* const* d_in, const int* in_sizes, int n_in,
                              void* d_out, int out_size, void* d_ws, size_t ws_size,
                              hipStream_t stream)
{
  const float* pred  = (const float*)d_in[0];
  const float* gt    = (const float*)d_in[1];
  const float* sigma = (const float*)d_in[2];
  char* ws = (char*)d_ws;
  // ws: Ah 2MB | Bh 2MB | gnorm 32KB | diag 32KB | ghs 32KB | partial 1MB | bsum
  unsigned char* Ah = (unsigned char*)(ws);
  unsigned char* Bh = (unsigned char*)(ws + (2u << 20));
  float* gnorm   = (float*)(ws + (4u << 20));
  float* diag    = (float*)(ws + (4u << 20) + (32u << 10));
  float* ghs     = (float*)(ws + (4u << 20) + (64u << 10));
  float* partial = (float*)(ws + (4u << 20) + (96u << 10));
  float* bsum    = (float*)(ws + (4u << 20) + (96u << 10) + (1u << 20));

  vmse_prep<<<NB / 4, 256, 0, stream>>>(pred, gt, sigma, Ah, Bh, diag, gnorm, ghs);
  vmse_main<<<32 * NCHUNK, 512, 0, stream>>>(Ah, Bh, ghs, partial);
  vmse_combine<<<NB / 256, 256, 0, stream>>>(partial, diag, gnorm, sigma, bsum);
  vmse_final<<<1, 64, 0, stream>>>(bsum, sigma, (float*)d_out);
}

// Round 11
// 44.379 us; speedup vs baseline: 5.0635x; 1.0199x over previous
//
#include <hip/hip_runtime.h>
#include <hip/hip_fp8.h>

// InfoNCE/contrastive MVN loss:
// loss = mean_i( LSE_j((p_i.g_j - 0.5|g_j|^2)/nv) - (p_i.g_i - 0.5|g_i|^2)/nv ) * 2nv
// B = 8192, D = 256, fp32 inputs, scalar fp32 output.
// Main kernel: fp8-e4m3 32x32x16 MFMA GEMM (P pre-scaled by s=log2e/nv) fused
// with online base-2 LSE. 32x32 shape: 2495 TF ceiling (vs 2075 for 16x16),
// half the instructions, and C/D layout gives each lane ONE pred col x 16 gt
// rows -> single (m,l) LSE state, one shfl_xor(32) merge. Whole 64KB G-panel
// staged once -> ONE barrier. Frag-pair-major fp8 layout: one ds_read_b128 =
// 2 k-step frags; quad-base pointers absorb the XOR swizzle.

typedef float f32x4 __attribute__((ext_vector_type(4)));
typedef float f32x16 __attribute__((ext_vector_type(16)));
typedef long llong2 __attribute__((ext_vector_type(2)));

#define LN2F 0.6931471805599453f
#define LOG2EF 1.4426950408889634f
#define NB 8192
#define ND 256
#define NCHUNK 32   // column chunks; chunk = 256 cols = 8 tiles of 32

#define AS1 __attribute__((address_space(1)))
#define AS3 __attribute__((address_space(3)))

__device__ __forceinline__ float fexp2(float x) {
#if __has_builtin(__builtin_amdgcn_exp2f)
  return __builtin_amdgcn_exp2f(x);   // raw v_exp_f32
#else
  float r;
  asm("v_exp_f32 %0, %1\n\ts_nop 1" : "=v"(r) : "v"(x));
  return r;
#endif
}

__device__ __forceinline__ int pack4_fp8(float a, float b, float c, float d) {
#if __has_builtin(__builtin_amdgcn_cvt_pk_fp8_f32)
  int w = __builtin_amdgcn_cvt_pk_fp8_f32(a, b, 0, false);
  w = __builtin_amdgcn_cvt_pk_fp8_f32(c, d, w, true);
  return w;
#else
  unsigned b0 = __hip_fp8_e4m3(a).__x, b1 = __hip_fp8_e4m3(b).__x;
  unsigned b2 = __hip_fp8_e4m3(c).__x, b3 = __hip_fp8_e4m3(d).__x;
  return (int)(b0 | (b1 << 8) | (b2 << 16) | (b3 << 24));
#endif
}

// ---- kernel 1: convert to fp8 (P pre-scaled, 32x32 frag-pair layout) -----
// pos(k) = (k>>5)*32 + ((k>>3)&1)*16 + ((k>>4)&1)*8 + (k&7): a b128 read at
// t2*32 + hi*16 yields k-step frags (2*t2, hi) and (2*t2+1, hi) back-to-back.
__global__ __launch_bounds__(256) void vmse_prep(
    const float* __restrict__ pred, const float* __restrict__ gt,
    const float* __restrict__ sigma,
    unsigned char* __restrict__ Ah, unsigned char* __restrict__ Bh,
    float* __restrict__ diag, float* __restrict__ gnorm,
    float* __restrict__ ghs)
{
  const float nv = sigma[0] * sigma[0];
  const float s = LOG2EF / nv;
  const int row = blockIdx.x * 4 + (threadIdx.x >> 6);
  const int l = threadIdx.x & 63;
  const float4 p = *(const float4*)(pred + row * ND + l * 4);
  const float4 g = *(const float4*)(gt   + row * ND + l * 4);
  const int pw = pack4_fp8(p.x * s, p.y * s, p.z * s, p.w * s);
  const int gw = pack4_fp8(g.x, g.y, g.z, g.w);
  // lane l covers k = 4l..4l+3 (same 8-slice):
  const int pos = (l >> 3) * 32 + ((l >> 1) & 1) * 16 + ((l >> 2) & 1) * 8 + (l & 1) * 4;
  *(int*)(Ah + row * ND + pos) = pw;
  *(int*)(Bh + row * ND + pos) = gw;
  float dd = p.x * g.x + p.y * g.y + p.z * g.z + p.w * g.w;
  float gg = g.x * g.x + g.y * g.y + g.z * g.z + g.w * g.w;
  #pragma unroll
  for (int off = 1; off < 64; off <<= 1) {
    dd += __shfl_xor(dd, off);
    gg += __shfl_xor(gg, off);
  }
  if (l == 0) {
    diag[row] = dd;                // exact fp32 p_i . g_i
    gnorm[row] = gg;
    ghs[row] = -0.5f * s * gg;     // NEGATED base-2 logit offset (acc init)
  }
}

// ---- kernel 2: fused fp8 32x32 GEMM + online base-2 LSE, one-barrier -----
// grid 1024 = 32 row-blocks x 32 column chunks. 512 threads = 8 waves,
// 2 blocks/CU (65KB LDS). Wave owns 32 pred rows (pf = 32 VGPR, 16 k-steps).
// Whole G panel (8 tiles x 32 rows x 256B) staged via 8 global_load_lds per
// thread (linear dest; source chunk = (l&15)^(row&7) pre-swizzle). ONE
// __syncthreads, then 128 MFMA/wave + epilogues, zero barriers.
// LDS read: physical chunk = ((t2<<1)|hi) ^ (row&7); quad base pointers
// pq[b] absorb bits 1-2, base absorbs bit 0, imm absorbs bit 3 + tile.
// mfma(G,P): C/D col=lane&31 -> pred, row=(reg&3)+8*(reg>>2)+4*hi -> gt.
__global__ __launch_bounds__(512, 4) void vmse_main(
    const unsigned char* __restrict__ Ah, const unsigned char* __restrict__ Bh,
    const float* __restrict__ ghs, float* __restrict__ partial)
{
  __shared__ unsigned char lds[8][32 * 256];   // 64 KB: whole column chunk
  __shared__ float lds_ghs[256];               // chunk's (negated) offsets
  const int tid = threadIdx.x;
  const int lane = tid & 63;
  const int wid = tid >> 6;
  const int rb = blockIdx.x & 31;     // row block (256 rows)
  const int ch = blockIdx.x >> 5;     // column chunk (256 cols)
  const int r31 = lane & 31;
  const int hi = lane >> 5;
  const int j0 = ch * 256;

  // stage the whole 64KB panel: tile t -> lds[t]; 1 instr/thread/tile.
  // lane l: row r = wid*4 + (l>>4), source chunk (l&15)^(r&7); dest linear.
  {
    const int r = wid * 4 + (lane >> 4);
    const int cg = (lane & 15) ^ (r & 7);
    const unsigned char* src = Bh + (size_t)(j0 + r) * ND + cg * 16;
    #pragma unroll
    for (int t = 0; t < 8; ++t)
      __builtin_amdgcn_global_load_lds(
          (const AS1 unsigned int*)(src + t * 8192),
          (AS3 unsigned int*)&lds[t][wid * 1024], 16, 0, 0);
  }
  if (tid < 256) lds_ghs[tid] = ghs[j0 + tid];

  // P fragments (pre-scaled fp8), B-operand: col = lane&31, k = hi*8+e.
  // b128 at t2*32 + hi*16 = frags (2t2, hi), (2t2+1, hi). 16 longs = 32 VGPR.
  long pf[16];
  {
    const unsigned char* prow = Ah + (size_t)((rb * 256) + (wid * 32) + r31) * ND;
    #pragma unroll
    for (int t2 = 0; t2 < 8; ++t2) {
      const llong2 v = *(const llong2*)(prow + t2 * 32 + hi * 16);
      pf[2 * t2] = v[0];
      pf[2 * t2 + 1] = v[1];
    }
  }

  // quad-base LDS read pointers for the gt A-frags
  const int r0b = r31 & 1;
  const int q2 = (r31 >> 1) & 3;
  const char* base = (const char*)&lds[0][0] + r31 * 256 + (hi ^ r0b) * 16;
  const char* pq[4];
  #pragma unroll
  for (int b = 0; b < 4; ++b) pq[b] = base + ((b ^ q2) * 32);

  float m2 = -3.0e38f, l2 = 0.0f;

  __syncthreads();   // the ONLY barrier: panel + ghs resident

  const char* gbase = (const char*)lds_ghs + hi * 16;
  #pragma unroll
  for (int tile = 0; tile < 8; ++tile) {
    // acc init = -0.5*s*|g_j|^2: reg quad q covers gt rows 8q+4hi+0..3
    f32x16 acc;
    #pragma unroll
    for (int q = 0; q < 4; ++q) {
      const f32x4 gv = *(const f32x4*)(gbase + tile * 128 + q * 32);
      acc[4 * q + 0] = gv[0];
      acc[4 * q + 1] = gv[1];
      acc[4 * q + 2] = gv[2];
      acc[4 * q + 3] = gv[3];
    }
    __builtin_amdgcn_s_setprio(1);
    #pragma unroll
    for (int a = 0; a < 2; ++a) {
      #pragma unroll
      for (int b = 0; b < 4; ++b) {
        const llong2 g = *(const llong2*)(pq[b] + a * 128 + tile * 8192);
        const int t = 2 * (a * 4 + b);
        acc = __builtin_amdgcn_mfma_f32_32x32x16_fp8_fp8(g[0], pf[t], acc, 0, 0, 0);
        acc = __builtin_amdgcn_mfma_f32_32x32x16_fp8_fp8(g[1], pf[t + 1], acc, 0, 0, 0);
      }
    }
    __builtin_amdgcn_s_setprio(0);
    // epilogue: 16 base-2 logits -> online LSE
    float mx0 = fmaxf(fmaxf(acc[0], acc[1]), fmaxf(acc[2], acc[3]));
    float mx1 = fmaxf(fmaxf(acc[4], acc[5]), fmaxf(acc[6], acc[7]));
    float mx2 = fmaxf(fmaxf(acc[8], acc[9]), fmaxf(acc[10], acc[11]));
    float mx3 = fmaxf(fmaxf(acc[12], acc[13]), fmaxf(acc[14], acc[15]));
    const float tmax = fmaxf(fmaxf(mx0, mx1), fmaxf(mx2, mx3));
    if (__any(tmax > m2 + 8.0f)) {      // T13 defer-max, rarely taken
      const float nm = fmaxf(m2, tmax);
      l2 *= fexp2(m2 - nm);
      m2 = nm;
    }
    float e0 = (fexp2(acc[0] - m2) + fexp2(acc[1] - m2)) +
               (fexp2(acc[2] - m2) + fexp2(acc[3] - m2));
    float e1 = (fexp2(acc[4] - m2) + fexp2(acc[5] - m2)) +
               (fexp2(acc[6] - m2) + fexp2(acc[7] - m2));
    float e2 = (fexp2(acc[8] - m2) + fexp2(acc[9] - m2)) +
               (fexp2(acc[10] - m2) + fexp2(acc[11] - m2));
    float e3 = (fexp2(acc[12] - m2) + fexp2(acc[13] - m2)) +
               (fexp2(acc[14] - m2) + fexp2(acc[15] - m2));
    l2 += (e0 + e1) + (e2 + e3);
  }

  // merge hi halves (same pred col, disjoint gt rows), write partial LSE
  {
    const float om = __shfl_xor(m2, 32);
    const float ol = __shfl_xor(l2, 32);
    const float nm = fmaxf(m2, om);
    l2 = l2 * fexp2(m2 - nm) + ol * fexp2(om - nm);
    m2 = nm;
    if (hi == 0) {
      const int row = rb * 256 + wid * 32 + r31;
      partial[row * NCHUNK + ch] = m2 + log2f(l2);
    }
  }
}

// ---- kernel 3: per-row combine of chunk partials + diagonal --------------
__global__ __launch_bounds__(256) void vmse_combine(
    const float* __restrict__ partial, const float* __restrict__ diag,
    const float* __restrict__ gnorm, const float* __restrict__ sigma,
    float* __restrict__ bsum)
{
  const int r = blockIdx.x * 256 + threadIdx.x;
  const float nv = sigma[0] * sigma[0];
  float p[NCHUNK];
  float M = -3.0e38f;
  #pragma unroll
  for (int c = 0; c < NCHUNK; ++c) { p[c] = partial[r * NCHUNK + c]; M = fmaxf(M, p[c]); }
  float ssum = 0.f;
  #pragma unroll
  for (int c = 0; c < NCHUNK; ++c) ssum += exp2f(p[c] - M);
  const float lse2 = M + log2f(ssum);          // base-2 LSE of z*log2e
  const float zii = (diag[r] - 0.5f * gnorm[r]) / nv;
  float contrib = LN2F * lse2 - zii;           // lse_e - z_ii
  #pragma unroll
  for (int off = 1; off < 64; off <<= 1) contrib += __shfl_xor(contrib, off);
  __shared__ float wsum[4];
  if ((threadIdx.x & 63) == 0) wsum[threadIdx.x >> 6] = contrib;
  __syncthreads();
  if (threadIdx.x == 0)
    bsum[blockIdx.x] = (wsum[0] + wsum[1]) + (wsum[2] + wsum[3]);
}

// ---- kernel 4: deterministic finalize ------------------------------------
__global__ __launch_bounds__(64) void vmse_final(
    const float* __restrict__ bsum, const float* __restrict__ sigma,
    float* __restrict__ out)
{
  const int lane = threadIdx.x;
  float v = (lane < 32) ? bsum[lane] : 0.f;
  #pragma unroll
  for (int off = 1; off < 64; off <<= 1) v += __shfl_xor(v, off);
  if (lane == 0) {
    const float nv = sigma[0] * sigma[0];
    out[0] = v * (2.0f * nv / (float)NB);
  }
}

extern "C" void kernel_launch(void* const* d_in, const int* in_sizes, int n_in,
                              void* d_out, int out_size, void* d_ws, size_t ws_size,
                              hipStream_t stream)
{
  const float* pred  = (const float*)d_in[0];
  const float* gt    = (const float*)d_in[1];
  const float* sigma = (const float*)d_in[2];
  char* ws = (char*)d_ws;
  // ws: Ah 2MB | Bh 2MB | gnorm 32KB | diag 32KB | ghs 32KB | partial 1MB | bsum
  unsigned char* Ah = (unsigned char*)(ws);
  unsigned char* Bh = (unsigned char*)(ws + (2u << 20));
  float* gnorm   = (float*)(ws + (4u << 20));
  float* diag    = (float*)(ws + (4u << 20) + (32u << 10));
  float* ghs     = (float*)(ws + (4u << 20) + (64u << 10));
  float* partial = (float*)(ws + (4u << 20) + (96u << 10));
  float* bsum    = (float*)(ws + (4u << 20) + (96u << 10) + (1u << 20));

  vmse_prep<<<NB / 4, 256, 0, stream>>>(pred, gt, sigma, Ah, Bh, diag, gnorm, ghs);
  vmse_main<<<32 * NCHUNK, 512, 0, stream>>>(Ah, Bh, ghs, partial);
  vmse_combine<<<NB / 256, 256, 0, stream>>>(partial, diag, gnorm, sigma, bsum);
  vmse_final<<<1, 64, 0, stream>>>(bsum, sigma, (float*)d_out);
}